// Round 1
// baseline (132.774 us; speedup 1.0000x reference)
//
#include <hip/hip_runtime.h>

// SingleRoIExtractor3D: temporal mean + aligned RoIAlign (avg), f32.
// feat: [N=4, C=2048, T=8, H=16, W=16] f32
// rois: [R=32, 5] f32  (bidx, x1, y1, x2, y2)
// out tuple: out0 [32,2048,1,16,16] then feat_p [4,2048,1,16,16]

#define NB   4
#define CCH  2048
#define TT   8
#define HH   16
#define WW   16
#define RR   32
#define OUTS 16
#define PIX  256          // OUTS*OUTS == HH*WW
#define CPB  8            // channels per block in roi kernel
#define SCALE (1.0f/16.0f)

// ---------------- Kernel 1: mean over T ----------------
// one float4 per thread over N*C*(H*W/4) = 524288 float4s
__global__ __launch_bounds__(256) void tmean_kernel(
    const float* __restrict__ feat, float* __restrict__ featp)
{
    int idx = blockIdx.x * 256 + threadIdx.x;   // float4 index
    int nc = idx >> 6;                          // which (n,c); 64 float4 per frame
    int q  = idx & 63;
    const float4* src = (const float4*)feat + (size_t)nc * (TT * 64) + q;
    float4 acc = src[0];
#pragma unroll
    for (int t = 1; t < TT; ++t) {
        float4 v = src[t * 64];
        acc.x += v.x; acc.y += v.y; acc.z += v.z; acc.w += v.w;
    }
    acc.x *= 0.125f; acc.y *= 0.125f; acc.z *= 0.125f; acc.w *= 0.125f;
    ((float4*)featp)[idx] = acc;
}

// ---------------- Kernel 2: aligned RoIAlign ----------------
// grid = R * (C/CPB) blocks of 256 threads; each block: one roi, CPB channels.
// Thread t computes output pixel t (oy=t>>4, ox=t&15) for each of CPB channels.
__global__ __launch_bounds__(256) void roialign_kernel(
    const float* __restrict__ featp, const float* __restrict__ rois,
    float* __restrict__ out)
{
    __shared__ float sfeat[CPB * PIX + 32];   // +pad so weight-0 overreads stay in-bounds
    const int bid = blockIdx.x;
    const int r   = bid >> 8;        // CCH/CPB = 256 channel-blocks per roi
    const int cb  = bid & 255;
    const int c0  = cb * CPB;
    const int tid = threadIdx.x;

    // ROI params (uniform across block; rois tiny, L2-resident)
    const int   bidx = (int)rois[r * 5 + 0];
    const float bx1  = rois[r * 5 + 1] * SCALE - 0.5f;
    const float by1  = rois[r * 5 + 2] * SCALE - 0.5f;
    const float bx2  = rois[r * 5 + 3] * SCALE - 0.5f;
    const float by2  = rois[r * 5 + 4] * SCALE - 0.5f;
    const float binh = (by2 - by1) * (1.0f / OUTS);
    const float binw = (bx2 - bx1) * (1.0f / OUTS);

    // stage CPB channels (2048 floats) into LDS, coalesced float4
    {
        const float4* src = (const float4*)(featp + ((size_t)bidx * CCH + c0) * PIX);
        float4* dst = (float4*)sfeat;
        dst[tid]       = src[tid];
        dst[tid + 256] = src[tid + 256];
        if (tid < 32) sfeat[CPB * PIX + tid] = 0.0f;   // zero the pad tail
    }
    __syncthreads();

    const int oy = tid >> 4, ox = tid & 15;

    // Per-dimension sample data for the 2 sub-samples in each dim.
    // Clamp identity: after clip to [0,15], y0==15 implies ly==0, so the
    // "y1" tap can always be row y0+1 (weight 0 at the edge) -> fixed 2x2
    // stencil {b, b+1, b+16, b+17}; overreads land in next channel / zero pad.
    float lyv[2], hyv[2], lxv[2], hxv[2];
    int   yb[2], xb[2];
    bool  vy[2], vx[2];
#pragma unroll
    for (int s = 0; s < 2; ++s) {
        float yy = by1 + ((float)(oy * 2 + s) + 0.5f) * 0.5f * binh;
        vy[s] = (yy >= -1.0f) && (yy <= (float)HH);
        float yc = fminf(fmaxf(yy, 0.0f), (float)(HH - 1));
        float y0f = floorf(yc);
        yb[s] = (int)y0f * WW;
        lyv[s] = yc - y0f; hyv[s] = 1.0f - lyv[s];

        float xx = bx1 + ((float)(ox * 2 + s) + 0.5f) * 0.5f * binw;
        vx[s] = (xx >= -1.0f) && (xx <= (float)WW);
        float xc = fminf(fmaxf(xx, 0.0f), (float)(WW - 1));
        float x0f = floorf(xc);
        xb[s] = (int)x0f;
        lxv[s] = xc - x0f; hxv[s] = 1.0f - lxv[s];
    }

    // 4 samples -> 16 (index,weight) taps, computed once, reused per channel
    int   base[4];
    float w00[4], w01[4], w10[4], w11[4];
#pragma unroll
    for (int sy = 0; sy < 2; ++sy)
#pragma unroll
        for (int sx = 0; sx < 2; ++sx) {
            int k = sy * 2 + sx;
            base[k] = yb[sy] + xb[sx];
            float m = (vy[sy] && vx[sx]) ? 1.0f : 0.0f;
            w00[k] = hyv[sy] * hxv[sx] * m;
            w01[k] = hyv[sy] * lxv[sx] * m;
            w10[k] = lyv[sy] * hxv[sx] * m;
            w11[k] = lyv[sy] * lxv[sx] * m;
        }

    size_t obase = ((size_t)r * CCH + c0) * PIX + tid;
#pragma unroll
    for (int ch = 0; ch < CPB; ++ch) {
        const float* f = sfeat + ch * PIX;
        float acc = 0.0f;
#pragma unroll
        for (int k = 0; k < 4; ++k) {
            acc += w00[k] * f[base[k]]      + w01[k] * f[base[k] + 1]
                 + w10[k] * f[base[k] + WW] + w11[k] * f[base[k] + WW + 1];
        }
        out[obase + (size_t)ch * PIX] = acc * 0.25f;
    }
}

extern "C" void kernel_launch(void* const* d_in, const int* in_sizes, int n_in,
                              void* d_out, int out_size, void* d_ws, size_t ws_size,
                              hipStream_t stream)
{
    const float* feat = (const float*)d_in[0];
    const float* rois = (const float*)d_in[1];
    float* out   = (float*)d_out;
    float* featp = out + (size_t)RR * CCH * PIX;   // second tuple output; also kernel2 input

    // N*C*(HW/4) / 256 = 2048 blocks
    tmean_kernel<<<2048, 256, 0, stream>>>(feat, featp);
    // R * C/CPB = 8192 blocks
    roialign_kernel<<<8192, 256, 0, stream>>>(featp, rois, out);
}

// Round 2
// 127.698 us; speedup vs baseline: 1.0398x; 1.0398x over previous
//
#include <hip/hip_runtime.h>

// SingleRoIExtractor3D: temporal mean + aligned RoIAlign (avg), f32.
// feat: [N=4, C=2048, T=8, H=16, W=16] f32
// rois: [R=32, 5] f32  (bidx, x1, y1, x2, y2)
// out tuple: out0 [32,2048,1,16,16] then feat_p [4,2048,1,16,16]

#define NB   4
#define CCH  2048
#define TT   8
#define HH   16
#define WW   16
#define RR   32
#define OUTS 16
#define PIX  256
#define SCALE (1.0f/16.0f)

// roialign LDS: 4 channels interleaved per pixel (float4), rows padded by one
// float4 -> 4-bank diagonal shift per row to break same-column conflicts.
#define ROWSTRIDE 68              // 16*4 + 4 pad floats
#define GSTRIDE   (16*ROWSTRIDE)  // 1088 floats per 4-channel group

// ---------------- Kernel 1: mean over T ----------------
__global__ __launch_bounds__(256) void tmean_kernel(
    const float* __restrict__ feat, float* __restrict__ featp)
{
    int idx = blockIdx.x * 256 + threadIdx.x;   // float4 index
    int nc = idx >> 6;                          // 64 float4 per frame
    int q  = idx & 63;
    const float4* src = (const float4*)feat + (size_t)nc * (TT * 64) + q;
    float4 acc = src[0];
#pragma unroll
    for (int t = 1; t < TT; ++t) {
        float4 v = src[t * 64];
        acc.x += v.x; acc.y += v.y; acc.z += v.z; acc.w += v.w;
    }
    acc.x *= 0.125f; acc.y *= 0.125f; acc.z *= 0.125f; acc.w *= 0.125f;
    ((float4*)featp)[idx] = acc;
}

// ---------------- Kernel 2: aligned RoIAlign ----------------
// Block: 1 roi x 8 channels (2 groups of 4, channel-interleaved in LDS).
// Thread t = output pixel t. 3x3 union stencil with separable weights
// wy[3] (x) wx[3]; one ds_read_b128 covers 4 channels per tap.
__global__ __launch_bounds__(256) void roialign_kernel(
    const float* __restrict__ featp, const float* __restrict__ rois,
    float* __restrict__ out)
{
    __shared__ float sf[2 * GSTRIDE];
    const int bid = blockIdx.x;
    const int r   = bid >> 8;          // 256 channel-blocks per roi
    const int c0  = (bid & 255) * 8;
    const int tid = threadIdx.x;

    const int   bidx = (int)rois[r * 5 + 0];
    const float bx1  = rois[r * 5 + 1] * SCALE - 0.5f;
    const float by1  = rois[r * 5 + 2] * SCALE - 0.5f;
    const float binw = (rois[r * 5 + 3] * SCALE - 0.5f - bx1) * (1.0f / OUTS);
    const float binh = (rois[r * 5 + 4] * SCALE - 0.5f - by1) * (1.0f / OUTS);

    // ---- stage 8 channels into channel-interleaved, row-padded LDS ----
    {
        const float4* src = (const float4*)(featp + ((size_t)bidx * CCH + c0) * PIX);
        int c  = tid >> 5;            // local channel 0..7
        int g  = c >> 2, c4 = c & 3;
        float* dst = sf + g * GSTRIDE + c4;
#pragma unroll
        for (int i = 0; i < 2; ++i) {
            int q = (tid & 31) + 32 * i;      // float4 index in channel, 0..63
            float4 v = src[c * 64 + q];
            int y = q >> 2, x4 = (q & 3) * 4; // 4 consecutive pixels x4..x4+3
            float* d = dst + y * ROWSTRIDE + x4 * 4;
            d[0] = v.x; d[4] = v.y; d[8] = v.z; d[12] = v.w;
        }
    }

    // ---- per-pixel separable 3x3 weights (independent of LDS) ----
    const int oy = tid >> 4, ox = tid & 15;
    int Y0, X0;
    float wy0, wy1, wy2, wx0, wx1, wx2;
    {
        float ya = by1 + ((float)(2 * oy) + 0.5f) * 0.5f * binh;
        float yb = ya + 0.5f * binh;
        float m  = (ya >= -1.0f && ya <= 16.0f) ? 1.0f : 0.0f;
        float yc = fminf(fmaxf(ya, 0.0f), 15.0f);
        float yf = floorf(yc);
        Y0 = (int)yf;
        float ly = yc - yf;
        wy0 = (1.0f - ly) * m; wy1 = ly * m; wy2 = 0.0f;
        m  = (yb >= -1.0f && yb <= 16.0f) ? 1.0f : 0.0f;
        yc = fminf(fmaxf(yb, 0.0f), 15.0f);
        yf = floorf(yc);
        ly = yc - yf;
        float hy2 = (1.0f - ly) * m, ly2 = ly * m;
        if ((int)yf > Y0) { wy1 += hy2; wy2 += ly2; }
        else              { wy0 += hy2; wy1 += ly2; }
        // fold the 1/4 sample average into wy
        wy0 *= 0.25f; wy1 *= 0.25f; wy2 *= 0.25f;
    }
    {
        float xa = bx1 + ((float)(2 * ox) + 0.5f) * 0.5f * binw;
        float xb = xa + 0.5f * binw;
        float m  = (xa >= -1.0f && xa <= 16.0f) ? 1.0f : 0.0f;
        float xc = fminf(fmaxf(xa, 0.0f), 15.0f);
        float xf = floorf(xc);
        X0 = (int)xf;
        float lx = xc - xf;
        wx0 = (1.0f - lx) * m; wx1 = lx * m; wx2 = 0.0f;
        m  = (xb >= -1.0f && xb <= 16.0f) ? 1.0f : 0.0f;
        xc = fminf(fmaxf(xb, 0.0f), 15.0f);
        xf = floorf(xc);
        lx = xc - xf;
        float hx2 = (1.0f - lx) * m, lx2 = lx * m;
        if ((int)xf > X0) { wx1 += hx2; wx2 += lx2; }
        else              { wx0 += hx2; wx1 += lx2; }
    }

    const float w00 = wy0 * wx0, w01 = wy0 * wx1, w02 = wy0 * wx2;
    const float w10 = wy1 * wx0, w11 = wy1 * wx1, w12 = wy1 * wx2;
    const float w20 = wy2 * wx0, w21 = wy2 * wx1, w22 = wy2 * wx2;

    // clamped tap indices (weight at a clamped duplicate position is 0,
    // matching the reference's min(x0+1, W-1) semantics exactly)
    const int xi0 = X0, xi1 = min(X0 + 1, 15), xi2 = min(X0 + 2, 15);
    const int yi0 = Y0, yi1 = min(Y0 + 1, 15), yi2 = min(Y0 + 2, 15);

    const bool needx2 = __any(wx2 > 0.0f);   // wave-uniform branches
    const bool needy2 = __any(wy2 > 0.0f);

    __syncthreads();

#define ACC(W, V) { float4 _t = (V); a.x += (W) * _t.x; a.y += (W) * _t.y; \
                    a.z += (W) * _t.z; a.w += (W) * _t.w; }

    float4 accg[2];
#pragma unroll
    for (int g = 0; g < 2; ++g) {
        const float* base = sf + g * GSTRIDE;
        const float4* r0 = (const float4*)(base + yi0 * ROWSTRIDE);
        const float4* r1 = (const float4*)(base + yi1 * ROWSTRIDE);
        const float4* r2 = (const float4*)(base + yi2 * ROWSTRIDE);
        float4 a = make_float4(0.f, 0.f, 0.f, 0.f);
        ACC(w00, r0[xi0]); ACC(w01, r0[xi1]);
        ACC(w10, r1[xi0]); ACC(w11, r1[xi1]);
        if (needx2) { ACC(w02, r0[xi2]); ACC(w12, r1[xi2]); }
        if (needy2) {
            ACC(w20, r2[xi0]); ACC(w21, r2[xi1]);
            if (needx2) ACC(w22, r2[xi2]);
        }
        accg[g] = a;
    }
#undef ACC

    const size_t ob = ((size_t)r * CCH + c0) * PIX + tid;
    out[ob + 0 * PIX] = accg[0].x;
    out[ob + 1 * PIX] = accg[0].y;
    out[ob + 2 * PIX] = accg[0].z;
    out[ob + 3 * PIX] = accg[0].w;
    out[ob + 4 * PIX] = accg[1].x;
    out[ob + 5 * PIX] = accg[1].y;
    out[ob + 6 * PIX] = accg[1].z;
    out[ob + 7 * PIX] = accg[1].w;
}

extern "C" void kernel_launch(void* const* d_in, const int* in_sizes, int n_in,
                              void* d_out, int out_size, void* d_ws, size_t ws_size,
                              hipStream_t stream)
{
    const float* feat = (const float*)d_in[0];
    const float* rois = (const float*)d_in[1];
    float* out   = (float*)d_out;
    float* featp = out + (size_t)RR * CCH * PIX;   // 2nd tuple output; kernel2 input

    tmean_kernel<<<2048, 256, 0, stream>>>(feat, featp);
    roialign_kernel<<<RR * 256, 256, 0, stream>>>(featp, rois, out);
}

// Round 3
// 127.321 us; speedup vs baseline: 1.0428x; 1.0030x over previous
//
#include <hip/hip_runtime.h>

// SingleRoIExtractor3D fused: temporal mean + aligned RoIAlign (avg), f32.
// feat: [N=4, C=2048, T=8, H=16, W=16] f32
// rois: [R=32, 5] f32  (bidx, x1, y1, x2, y2)
// out tuple: out0 [32,2048,1,16,16] then feat_p [4,2048,1,16,16]
//
// One kernel: block = (image n, 8 channels). Computes the T-mean in registers
// (writes feat_p once), stages it channel-interleaved into LDS, then loops
// over the ROIs belonging to image n doing a separable 3x3-union gather
// (one ds_read_b128 serves 4 channels per tap).

#define NB   4
#define CCH  2048
#define TT   8
#define RR   32
#define PIX  256
#define SCALE (1.0f/16.0f)

// LDS: 4 channels interleaved per pixel (float4); rows padded by one float4
// -> 4-bank diagonal shift per row to break same-column conflicts.
#define ROWSTRIDE 68              // 16*4 + 4 pad floats
#define GSTRIDE   (16*ROWSTRIDE)  // floats per 4-channel group

__global__ __launch_bounds__(256) void fused_roi_kernel(
    const float* __restrict__ feat, const float* __restrict__ rois,
    float* __restrict__ out, float* __restrict__ featp)
{
    __shared__ float sf[2 * GSTRIDE];
    __shared__ float srois[RR * 5];

    const int tid = threadIdx.x;
    const int n   = blockIdx.x >> 8;          // image
    const int c0  = (blockIdx.x & 255) * 8;   // first of 8 channels

    if (tid < RR * 5) srois[tid] = rois[tid];

    // ---- temporal mean of 8 channels: write feat_p + stage into LDS ----
    // wave w handles channels {w, w+4}; each wave-load is one full 1KB frame.
    {
        const int q  = tid & 63;              // float4 column within frame
        const int w  = tid >> 6;              // wave id 0..3
        const int y  = q >> 2;
        const int x4 = (q & 3) * 4;
#pragma unroll
        for (int cc = 0; cc < 2; ++cc) {
            const int c = w + cc * 4;         // group g = cc, lane-in-group = w
            const float4* src = (const float4*)feat +
                (size_t)(n * CCH + c0 + c) * (TT * 64);
            float4 a = src[q];
#pragma unroll
            for (int t = 1; t < TT; ++t) {
                float4 v = src[t * 64 + q];
                a.x += v.x; a.y += v.y; a.z += v.z; a.w += v.w;
            }
            a.x *= 0.125f; a.y *= 0.125f; a.z *= 0.125f; a.w *= 0.125f;
            ((float4*)featp)[(size_t)(n * CCH + c0 + c) * 64 + q] = a;
            float* d = sf + cc * GSTRIDE + y * ROWSTRIDE + x4 * 4 + w;
            d[0] = a.x; d[4] = a.y; d[8] = a.z; d[12] = a.w;
        }
    }
    __syncthreads();

    const int oy = tid >> 4, ox = tid & 15;

    for (int r = 0; r < RR; ++r) {
        if ((int)srois[r * 5] != n) continue;   // block-uniform branch

        const float bx1  = srois[r*5+1] * SCALE - 0.5f;
        const float by1  = srois[r*5+2] * SCALE - 0.5f;
        const float binw = (srois[r*5+3] * SCALE - 0.5f - bx1) * (1.0f/16.0f);
        const float binh = (srois[r*5+4] * SCALE - 0.5f - by1) * (1.0f/16.0f);

        // ---- per-pixel separable 3x3 weights ----
        int Y0, X0;
        float wy0, wy1, wy2, wx0, wx1, wx2;
        {
            float ya = by1 + ((float)(2 * oy) + 0.5f) * 0.5f * binh;
            float yb = ya + 0.5f * binh;
            float m  = (ya >= -1.0f && ya <= 16.0f) ? 1.0f : 0.0f;
            float yc = fminf(fmaxf(ya, 0.0f), 15.0f);
            float yf = floorf(yc);
            Y0 = (int)yf;
            float ly = yc - yf;
            wy0 = (1.0f - ly) * m; wy1 = ly * m; wy2 = 0.0f;
            m  = (yb >= -1.0f && yb <= 16.0f) ? 1.0f : 0.0f;
            yc = fminf(fmaxf(yb, 0.0f), 15.0f);
            yf = floorf(yc);
            ly = yc - yf;
            float hy2 = (1.0f - ly) * m, ly2 = ly * m;
            if ((int)yf > Y0) { wy1 += hy2; wy2 += ly2; }
            else              { wy0 += hy2; wy1 += ly2; }
            wy0 *= 0.25f; wy1 *= 0.25f; wy2 *= 0.25f;  // fold 1/4 sample avg
        }
        {
            float xa = bx1 + ((float)(2 * ox) + 0.5f) * 0.5f * binw;
            float xb = xa + 0.5f * binw;
            float m  = (xa >= -1.0f && xa <= 16.0f) ? 1.0f : 0.0f;
            float xc = fminf(fmaxf(xa, 0.0f), 15.0f);
            float xf = floorf(xc);
            X0 = (int)xf;
            float lx = xc - xf;
            wx0 = (1.0f - lx) * m; wx1 = lx * m; wx2 = 0.0f;
            m  = (xb >= -1.0f && xb <= 16.0f) ? 1.0f : 0.0f;
            xc = fminf(fmaxf(xb, 0.0f), 15.0f);
            xf = floorf(xc);
            lx = xc - xf;
            float hx2 = (1.0f - lx) * m, lx2 = lx * m;
            if ((int)xf > X0) { wx1 += hx2; wx2 += lx2; }
            else              { wx0 += hx2; wx1 += lx2; }
        }

        const float w00 = wy0 * wx0, w01 = wy0 * wx1, w02 = wy0 * wx2;
        const float w10 = wy1 * wx0, w11 = wy1 * wx1, w12 = wy1 * wx2;
        const float w20 = wy2 * wx0, w21 = wy2 * wx1, w22 = wy2 * wx2;

        // clamped tap indices (weight at clamped duplicate is 0, matching
        // the reference's min(x0+1, W-1) semantics exactly)
        const int xi0 = X0, xi1 = min(X0 + 1, 15), xi2 = min(X0 + 2, 15);
        const int yi0 = Y0, yi1 = min(Y0 + 1, 15), yi2 = min(Y0 + 2, 15);

        const bool needx2 = __any(wx2 > 0.0f);   // wave-uniform
        const bool needy2 = __any(wy2 > 0.0f);

#define ACC(W, V) { float4 _t = (V); a.x += (W) * _t.x; a.y += (W) * _t.y; \
                    a.z += (W) * _t.z; a.w += (W) * _t.w; }
        float4 accg[2];
#pragma unroll
        for (int g = 0; g < 2; ++g) {
            const float* base = sf + g * GSTRIDE;
            const float4* r0 = (const float4*)(base + yi0 * ROWSTRIDE);
            const float4* r1 = (const float4*)(base + yi1 * ROWSTRIDE);
            const float4* r2 = (const float4*)(base + yi2 * ROWSTRIDE);
            float4 a = make_float4(0.f, 0.f, 0.f, 0.f);
            ACC(w00, r0[xi0]); ACC(w01, r0[xi1]);
            ACC(w10, r1[xi0]); ACC(w11, r1[xi1]);
            if (needx2) { ACC(w02, r0[xi2]); ACC(w12, r1[xi2]); }
            if (needy2) {
                ACC(w20, r2[xi0]); ACC(w21, r2[xi1]);
                if (needx2) ACC(w22, r2[xi2]);
            }
            accg[g] = a;
        }
#undef ACC

        const size_t ob = ((size_t)r * CCH + c0) * PIX + tid;
        out[ob + 0 * PIX] = accg[0].x;
        out[ob + 1 * PIX] = accg[0].y;
        out[ob + 2 * PIX] = accg[0].z;
        out[ob + 3 * PIX] = accg[0].w;
        out[ob + 4 * PIX] = accg[1].x;
        out[ob + 5 * PIX] = accg[1].y;
        out[ob + 6 * PIX] = accg[1].z;
        out[ob + 7 * PIX] = accg[1].w;
    }
}

extern "C" void kernel_launch(void* const* d_in, const int* in_sizes, int n_in,
                              void* d_out, int out_size, void* d_ws, size_t ws_size,
                              hipStream_t stream)
{
    const float* feat = (const float*)d_in[0];
    const float* rois = (const float*)d_in[1];
    float* out   = (float*)d_out;
    float* featp = out + (size_t)RR * CCH * PIX;   // 2nd tuple output

    // NB * (CCH/8) = 1024 blocks
    fused_roi_kernel<<<NB * 256, 256, 0, stream>>>(feat, rois, out, featp);
}